// Round 9
// baseline (1423.724 us; speedup 1.0000x reference)
//
#include <hip/hip_runtime.h>
#include <hip/hip_bf16.h>
#include <hip/hip_fp16.h>

typedef _Float16 f16;
typedef f16 f16x8 __attribute__((ext_vector_type(8)));
typedef float f32x4 __attribute__((ext_vector_type(4)));

#define LL 512
#define BB 32
#define DD 512
#define MM (LL * BB) /* 16384 */

// async global->LDS, 16B per lane; lds base must be wave-uniform
__device__ __forceinline__ void gl16(const f16* g, f16* l) {
  __builtin_amdgcn_global_load_lds(
      (const __attribute__((address_space(1))) void*)g,
      (__attribute__((address_space(3))) void*)l, 16, 0, 0);
}

// ---- transpose+convert fp32 (K,N) -> f16 (N,K), with SRU slice-plane permutation ----
template <int KS>
__global__ __launch_bounds__(256) void k_transpose_perm(const float* __restrict__ in,
                                                        f16* __restrict__ out, int K, int N) {
  __shared__ float tile[32][33];
  size_t bo = (size_t)blockIdx.z * (size_t)K * N;
  const int PD = 512 * KS;
  int n0 = blockIdx.x * 32, k0 = blockIdx.y * 32;
  int tx = threadIdx.x, ty = threadIdx.y;
#pragma unroll
  for (int s = 0; s < 4; ++s)
    tile[ty + s * 8][tx] = in[bo + (size_t)(k0 + ty + s * 8) * N + n0 + tx];
  __syncthreads();
#pragma unroll
  for (int s = 0; s < 4; ++s) {
    int n = n0 + ty + s * 8;
    int dir = n / PD, w = n % PD;
    int orow = dir * PD + (w % KS) * 512 + (w / KS);
    out[bo + (size_t)orow * K + k0 + tx] = (f16)tile[tx][ty + s * 8];
  }
}

// ---- transpose+convert lin2_w (1024,144) f32 -> (144,1024) f16 ----
__global__ __launch_bounds__(256) void k_transpose2(const float* __restrict__ in,
                                                    f16* __restrict__ out) {
  __shared__ float tile[32][33];
  int n0 = blockIdx.x * 32, k0 = blockIdx.y * 32;
  int tx = threadIdx.x, ty = threadIdx.y;
#pragma unroll
  for (int s = 0; s < 4; ++s) {
    int n = n0 + tx;
    tile[ty + s * 8][tx] = (n < 144) ? in[(size_t)(k0 + ty + s * 8) * 144 + n] : 0.f;
  }
  __syncthreads();
#pragma unroll
  for (int s = 0; s < 4; ++s) {
    int n = n0 + ty + s * 8;
    if (n < 144) out[(size_t)n * 1024 + k0 + tx] = (f16)tile[tx][ty + s * 8];
  }
}

// ---- lin1: yH = relu(x @ w + b) as f16, x (M,72), w (72,512) ----
__global__ __launch_bounds__(256) void k_lin1(const float* __restrict__ x,
                                              const float* __restrict__ w,
                                              const float* __restrict__ bias,
                                              f16* __restrict__ yH) {
  __shared__ float xs[8][72];
  int m0 = blockIdx.x * 8;
  int t = threadIdx.x;
  if (t < 144) {
    int row = t / 18, c4 = (t % 18) * 4;
    float4 v = *(const float4*)(x + (size_t)(m0 + row) * 72 + c4);
    xs[row][c4] = v.x; xs[row][c4 + 1] = v.y; xs[row][c4 + 2] = v.z; xs[row][c4 + 3] = v.w;
  }
  __syncthreads();
  int j0 = t, j1 = t + 256;
  float b0 = bias[j0], b1 = bias[j1];
  float acc[8][2];
#pragma unroll
  for (int r = 0; r < 8; ++r) { acc[r][0] = b0; acc[r][1] = b1; }
  for (int k = 0; k < 72; ++k) {
    float w0 = w[k * 512 + j0], w1 = w[k * 512 + j1];
#pragma unroll
    for (int r = 0; r < 8; ++r) {
      acc[r][0] = fmaf(xs[r][k], w0, acc[r][0]);
      acc[r][1] = fmaf(xs[r][k], w1, acc[r][1]);
    }
  }
#pragma unroll
  for (int r = 0; r < 8; ++r) {
    yH[(size_t)(m0 + r) * 512 + j0] = (f16)fmaxf(acc[r][0], 0.f);
    yH[(size_t)(m0 + r) * 512 + j1] = (f16)fmaxf(acc[r][1], 0.f);
  }
}

// ---- LayerNorm f16 -> f16 (one block per row), stats in f32 ----
template <int W>
__global__ __launch_bounds__(256) void k_ln(const f16* __restrict__ in,
                                            const float* __restrict__ g,
                                            const float* __restrict__ be,
                                            f16* __restrict__ out) {
  constexpr int V = W / 256;  // 2 or 4
  int row = blockIdx.x, t = threadIdx.x;
  const f16* p = in + (size_t)row * W + t * V;
  float v[V];
  if constexpr (V == 4) {
    union { uint2 u; f16 h[4]; } pk;
    pk.u = *(const uint2*)p;
#pragma unroll
    for (int i = 0; i < 4; ++i) v[i] = (float)pk.h[i];
  } else {
    union { unsigned u; f16 h[2]; } pk;
    pk.u = *(const unsigned*)p;
    v[0] = (float)pk.h[0]; v[1] = (float)pk.h[1];
  }
  float s = 0.f, ss = 0.f;
#pragma unroll
  for (int i = 0; i < V; ++i) { s += v[i]; ss += v[i] * v[i]; }
#pragma unroll
  for (int o = 32; o > 0; o >>= 1) { s += __shfl_down(s, o); ss += __shfl_down(ss, o); }
  __shared__ float red[10];
  if ((t & 63) == 0) { red[(t >> 6) * 2] = s; red[(t >> 6) * 2 + 1] = ss; }
  __syncthreads();
  if (t == 0) {
    float S = red[0] + red[2] + red[4] + red[6];
    float SS = red[1] + red[3] + red[5] + red[7];
    float mean = S / W;
    float var = SS / W - mean * mean;
    red[8] = mean; red[9] = rsqrtf(var + 1e-5f);
  }
  __syncthreads();
  float mean = red[8], rstd = red[9];
  if constexpr (V == 4) {
    union { f16 h[4]; uint2 u; } pk;
#pragma unroll
    for (int i = 0; i < 4; ++i) {
      int col = t * 4 + i;
      pk.h[i] = (f16)((v[i] - mean) * rstd * g[col] + be[col]);
    }
    *(uint2*)(out + (size_t)row * W + t * 4) = pk.u;
  } else {
    union { f16 h[2]; unsigned u; } pk;
#pragma unroll
    for (int i = 0; i < 2; ++i) {
      int col = t * 2 + i;
      pk.h[i] = (f16)((v[i] - mean) * rstd * g[col] + be[col]);
    }
    *(unsigned*)(out + (size_t)row * W + t * 2) = pk.u;
  }
}

// ---- pipelined GEMM: 128x128 tile, BK=32, 4-slot LDS ring, counted vmcnt ----
// LDS chunk-plane layout: elem(row,c) = (row>>4)*512 + (c*16 + (row&15))*8.
// Staging pre-permutes the GLOBAL source (gl_lds dest stays linear); a full wave's
// frag read covers 64 distinct contiguous 16B chunks = conflict-free.
// Ring: iter t stages tile t+3 into slot (t+3)&3 (freed at the barrier ending iter
// t-1); vmcnt(8) at iter end keeps tiles t+2,t+3 in flight (never drains to 0).
template <int K>
__global__ __launch_bounds__(256, 2) void k_gemmp(const f16* __restrict__ A,
                                                  const f16* __restrict__ BT,
                                                  f16* __restrict__ C, int N) {
  constexpr int NT = K / 32;
  __shared__ __align__(16) f16 lds[32768];  // 64 KB: A slots [0,16384), B slots [16384,32768)
  const int tid = threadIdx.x, lane = tid & 63, wave = tid >> 6;
  const int wr = wave >> 1, wc = wave & 1;

  // XCD-bijective block swizzle (grid size % 8 == 0 for all our grids)
  const int nx = gridDim.x;
  int nwg = nx * gridDim.y;
  int bid = blockIdx.y * nx + blockIdx.x;
  int wg = (bid & 7) * (nwg >> 3) + (bid >> 3);
  int n0 = (wg % nx) * 128, m0 = (wg / nx) * 128;

  // staging map: thread tid fetches global (row r1, 16B-chunk c1) and (r1+64, c1)
  const int r1 = ((tid >> 6) << 4) | (tid & 15);
  const int c1 = (tid >> 4) & 3;
  const f16* Asrc = A + (size_t)(m0 + r1) * K + c1 * 8;
  const f16* Bsrc = BT + (size_t)(n0 + r1) * K + c1 * 8;
  const int K64 = 64 * K;

  // frag-read offset: lane (c=l>>4, fr=l&15) -> chunk c*16+fr within its 16-row block
  const int rdA = ((lane >> 4) << 4) | (lane & 15);
  const int fA = wr * 2048 + rdA * 8;            // + i*512 per m-frag
  const int fB = 16384 + wc * 2048 + rdA * 8;    // + j*512 per n-frag

  f32x4 acc[4][4] = {};

#define STAGE(t)                                                \
  {                                                             \
    const f16* a_ = Asrc + (t) * 32;                            \
    const f16* b_ = Bsrc + (t) * 32;                            \
    f16* d_ = lds + (((t) & 3) << 12) + wave * 512;             \
    gl16(a_, d_);                                               \
    gl16(a_ + K64, d_ + 2048);                                  \
    gl16(b_, d_ + 16384);                                       \
    gl16(b_ + K64, d_ + 18432);                                 \
  }

  STAGE(0) STAGE(1) STAGE(2)
  asm volatile("s_waitcnt vmcnt(8)" ::: "memory");  // tile 0 landed (12 -> 8 outstanding)
  __builtin_amdgcn_s_barrier();

#define GITER(t, DOSTAGE, VMN, DOBAR)                                         \
  {                                                                           \
    if (DOSTAGE) STAGE((t) + 3);                                              \
    const int sb = (((t) & 3) << 12);                                         \
    f16x8 af[4], bf[4];                                                       \
    _Pragma("unroll") for (int i = 0; i < 4; ++i)                             \
        af[i] = *(const f16x8*)&lds[sb + fA + i * 512];                       \
    _Pragma("unroll") for (int j = 0; j < 4; ++j)                             \
        bf[j] = *(const f16x8*)&lds[sb + fB + j * 512];                       \
    __builtin_amdgcn_s_setprio(1);                                            \
    _Pragma("unroll") for (int i = 0; i < 4; ++i)                             \
        _Pragma("unroll") for (int j = 0; j < 4; ++j)                         \
            acc[i][j] = __builtin_amdgcn_mfma_f32_16x16x32_f16(               \
                af[i], bf[j], acc[i][j], 0, 0, 0);                            \
    __builtin_amdgcn_s_setprio(0);                                            \
    __builtin_amdgcn_sched_barrier(0);                                        \
    if ((VMN) == 8) { asm volatile("s_waitcnt vmcnt(8)" ::: "memory"); }      \
    else if ((VMN) == 4) { asm volatile("s_waitcnt vmcnt(4)" ::: "memory"); } \
    else if ((VMN) == 0) { asm volatile("s_waitcnt vmcnt(0)" ::: "memory"); } \
    if (DOBAR) __builtin_amdgcn_s_barrier();                                  \
  }

#pragma unroll 1
  for (int t = 0; t < NT - 3; ++t) GITER(t, true, 8, true)
  GITER(NT - 3, false, 4, true)
  GITER(NT - 2, false, 0, true)
  GITER(NT - 1, false, -1, false)
#undef GITER
#undef STAGE

  const int fr = lane & 15, q = lane >> 4;
  int col = n0 + wc * 64 + fr;
  int rb = m0 + wr * 64 + q * 4;
#pragma unroll
  for (int i = 0; i < 4; ++i)
#pragma unroll
    for (int j = 0; j < 4; ++j)
#pragma unroll
      for (int r = 0; r < 4; ++r)
        C[(size_t)(rb + i * 16 + r) * N + col + j * 16] = (f16)acc[i][j][r];
}

// ---- SRU scan: 8-deep load ring + 16-deep h ring (store at +8, reuse at +16) ----
template <int KK>
__global__ __launch_bounds__(64) void k_scan(const f16* __restrict__ U,
                                             const f16* __restrict__ xln,
                                             const float* __restrict__ wcp,
                                             const float* __restrict__ bp,
                                             f16* __restrict__ yH,
                                             float* __restrict__ cs) {
  int tid = blockIdx.x * 64 + threadIdx.x;  // 0..32767
  int dir = tid >> 14, b = (tid >> 9) & 31, d = tid & 511;
  int col = (dir << 9) + d;
  const int N = 1024 * KK;
  const f16* base = U + dir * (512 * KK) + d;
  const f16* rbase = (KK == 4) ? base + 1536 : xln + col;
  const long rstride = (KK == 4) ? N : 1024;
  float wcf = wcp[col], wcr = wcp[1024 + col];
  float bfv = bp[col], brv = bp[1024 + col];
  float c = 0.f;
  f16 ru0[8], ru1[8], ru2[8], rr[8];
  float hh[16];

  const long sgn = dir ? -32L : 32L;
  const long sN = sgn * N, sR = sgn * rstride, sY = sgn * 1024;
  long row0 = ((long)(dir ? 511 : 0) << 5) + b;
  const f16* pL = base + (size_t)row0 * N;
  const f16* pR = rbase + (size_t)row0 * rstride;
#pragma unroll
  for (int i = 0; i < 8; ++i) {
    ru0[i] = pL[0]; ru1[i] = pL[512]; ru2[i] = pL[1024];
    rr[i] = *pR;
    pL += sN; pR += sR;
  }
  f16* pS = yH + (size_t)row0 * 1024 + col;

#define BODY(i, DO_STORE, DO_PRE)                                        \
  {                                                                      \
    float u0 = (float)ru0[(i) & 7], u1 = (float)ru1[(i) & 7],            \
          u2 = (float)ru2[(i) & 7], res = (float)rr[(i) & 7];            \
    if (DO_STORE) {                                                      \
      *pS = (f16)hh[((i) + 8) & 15];                                     \
      pS += sY;                                                          \
      __builtin_amdgcn_sched_barrier(0);                                 \
    }                                                                    \
    if (DO_PRE) {                                                        \
      ru0[(i) & 7] = pL[0]; ru1[(i) & 7] = pL[512];                      \
      ru2[(i) & 7] = pL[1024]; rr[(i) & 7] = *pR;                        \
      pL += sN; pR += sR;                                                \
    }                                                                    \
    float zf = u1 + wcf * c + bfv;                                       \
    float f = __builtin_amdgcn_rcpf(1.f + __expf(-zf));                  \
    c = f * c + (1.f - f) * u0;                                          \
    float zr = u2 + wcr * c + brv;                                       \
    float r = __builtin_amdgcn_rcpf(1.f + __expf(-zr));                  \
    hh[(i) & 15] = r * c + (1.f - r) * res;                              \
  }

#pragma unroll
  for (int i = 0; i < 16; ++i) BODY(i, (i >= 8), true);
  for (int t0 = 16; t0 < 496; t0 += 16) {
#pragma unroll
    for (int i = 0; i < 16; ++i) BODY(i, true, true);
  }
#pragma unroll
  for (int i = 0; i < 16; ++i) BODY(i, true, (i < 8));
#pragma unroll
  for (int j = 8; j < 16; ++j) { *pS = (f16)hh[j]; pS += sY; }
  cs[b * 1024 + col] = c;
#undef BODY
}

// ---- lin2 via MFMA: out(M,144) f32 = Y(M,1024) f16 @ WT(144,1024)^T + bias ----
__global__ __launch_bounds__(256) void k_lin2m(const f16* __restrict__ Y,
                                               const f16* __restrict__ WT,
                                               const float* __restrict__ bias,
                                               float* __restrict__ out) {
  __shared__ __align__(16) f16 lA[64 * 32];
  int m0 = blockIdx.x * 64;
  int tid = threadIdx.x, lane = tid & 63, wave = tid >> 6;
  int fr = lane & 15, kq = (lane >> 4) * 8;
  f32x4 acc[9] = {};
  int srow = wave * 16 + (lane >> 2);
  int skel = (lane & 3) * 8;
  const f16* Yp = Y + (size_t)(m0 + srow) * 1024 + skel;
  f16* ldst = lA + wave * 512;
  for (int k0 = 0; k0 < 1024; k0 += 32) {
    if (k0) __syncthreads();
    gl16(Yp + k0, ldst);
    f16x8 bf[9];
#pragma unroll
    for (int j = 0; j < 9; ++j)
      bf[j] = *(const f16x8*)(WT + (size_t)(j * 16 + fr) * 1024 + k0 + kq);
    __syncthreads();
    f16x8 af = *(const f16x8*)&lA[(wave * 16 + fr) * 32 + kq];
#pragma unroll
    for (int j = 0; j < 9; ++j)
      acc[j] = __builtin_amdgcn_mfma_f32_16x16x32_f16(af, bf[j], acc[j], 0, 0, 0);
  }
  int rb = m0 + wave * 16 + (lane >> 4) * 4;
#pragma unroll
  for (int j = 0; j < 9; ++j) {
    float bv = bias[j * 16 + fr];
#pragma unroll
    for (int r = 0; r < 4; ++r)
      out[(size_t)(rb + r) * 144 + j * 16 + fr] = acc[j][r] + bv;
  }
}

extern "C" void kernel_launch(void* const* d_in, const int* in_sizes, int n_in,
                              void* d_out, int out_size, void* d_ws, size_t ws_size,
                              hipStream_t stream) {
  const float* x      = (const float*)d_in[0];
  const float* lin1_w = (const float*)d_in[1];
  const float* lin1_b = (const float*)d_in[2];
  const float* lin2_w = (const float*)d_in[3];
  const float* lin2_b = (const float*)d_in[4];
  const float* W0     = (const float*)d_in[5];
  const float* wc0    = (const float*)d_in[6];
  const float* b0     = (const float*)d_in[7];
  const float* ln0_g  = (const float*)d_in[8];
  const float* ln0_b  = (const float*)d_in[9];
  const float* Wl     = (const float*)d_in[10];
  const float* wcl    = (const float*)d_in[11];
  const float* bl     = (const float*)d_in[12];
  const float* lnl_g  = (const float*)d_in[13];
  const float* lnl_b  = (const float*)d_in[14];
  float* out = (float*)d_out;

  // workspace layout (252 MB)
  char* ws = (char*)d_ws;
  f16* yH  = (f16*)(ws);                       // (16384,1024) f16, 32 MB
  f16* A16 = (f16*)(ws + ((size_t)32 << 20));  // (16384,1024) f16, 32 MB
  f16* C16 = (f16*)(ws + ((size_t)64 << 20));  // (16384,4096) f16, up to 128 MB
  f16* WT2 = (f16*)(ws + ((size_t)192 << 20)); // (144,1024) f16
  f16* W0T = (f16*)(ws + ((size_t)224 << 20)); // (4096,512) f16, 4 MB
  f16* WlT = (f16*)(ws + ((size_t)228 << 20)); // 4 x (3072,1024) f16, 24 MB

  k_transpose_perm<4><<<dim3(128, 16, 1), dim3(32, 8), 0, stream>>>(W0, W0T, 512, 4096);
  k_transpose_perm<3><<<dim3(96, 32, 4), dim3(32, 8), 0, stream>>>(Wl, WlT, 1024, 3072);

  k_lin1<<<MM / 8, 256, 0, stream>>>(x, lin1_w, lin1_b, yH);

  // layer 0 (k=4)
  k_ln<512><<<MM, 256, 0, stream>>>(yH, ln0_g, ln0_b, A16);
  k_gemmp<512><<<dim3(32, 128), 256, 0, stream>>>(A16, W0T, C16, 4096);
  k_scan<4><<<512, 64, 0, stream>>>(C16, (const f16*)nullptr, wc0, b0, yH, out + 2359296);

  k_transpose2<<<dim3(5, 32), dim3(32, 8), 0, stream>>>(lin2_w, WT2);

  // layers 1..4 (k=3)
  for (int i = 0; i < 4; ++i) {
    k_ln<1024><<<MM, 256, 0, stream>>>(yH, lnl_g + i * 1024, lnl_b + i * 1024, A16);
    k_gemmp<1024><<<dim3(24, 128), 256, 0, stream>>>(A16, WlT + (size_t)i * 3072 * 1024, C16, 3072);
    k_scan<3><<<512, 64, 0, stream>>>(C16, A16, wcl + i * 2048, bl + i * 2048, yH,
                                      out + 2359296 + (size_t)(i + 1) * 32768);
  }

  k_lin2m<<<MM / 64, 256, 0, stream>>>(yH, WT2, lin2_b, out);
}

// Round 10
// 1401.022 us; speedup vs baseline: 1.0162x; 1.0162x over previous
//
#include <hip/hip_runtime.h>
#include <hip/hip_bf16.h>
#include <hip/hip_fp16.h>

typedef _Float16 f16;
typedef f16 f16x8 __attribute__((ext_vector_type(8)));
typedef float f32x4 __attribute__((ext_vector_type(4)));

#define LL 512
#define BB 32
#define DD 512
#define MM (LL * BB) /* 16384 */

// async global->LDS, 16B per lane; lds base must be wave-uniform
__device__ __forceinline__ void gl16(const f16* g, f16* l) {
  __builtin_amdgcn_global_load_lds(
      (const __attribute__((address_space(1))) void*)g,
      (__attribute__((address_space(3))) void*)l, 16, 0, 0);
}

// ---- transpose+convert fp32 (K,N) -> f16 (N,K), with SRU slice-plane permutation ----
template <int KS>
__global__ __launch_bounds__(256) void k_transpose_perm(const float* __restrict__ in,
                                                        f16* __restrict__ out, int K, int N) {
  __shared__ float tile[32][33];
  size_t bo = (size_t)blockIdx.z * (size_t)K * N;
  const int PD = 512 * KS;
  int n0 = blockIdx.x * 32, k0 = blockIdx.y * 32;
  int tx = threadIdx.x, ty = threadIdx.y;
#pragma unroll
  for (int s = 0; s < 4; ++s)
    tile[ty + s * 8][tx] = in[bo + (size_t)(k0 + ty + s * 8) * N + n0 + tx];
  __syncthreads();
#pragma unroll
  for (int s = 0; s < 4; ++s) {
    int n = n0 + ty + s * 8;
    int dir = n / PD, w = n % PD;
    int orow = dir * PD + (w % KS) * 512 + (w / KS);
    out[bo + (size_t)orow * K + k0 + tx] = (f16)tile[tx][ty + s * 8];
  }
}

// ---- transpose+convert lin2_w (1024,144) f32 -> (144,1024) f16 ----
__global__ __launch_bounds__(256) void k_transpose2(const float* __restrict__ in,
                                                    f16* __restrict__ out) {
  __shared__ float tile[32][33];
  int n0 = blockIdx.x * 32, k0 = blockIdx.y * 32;
  int tx = threadIdx.x, ty = threadIdx.y;
#pragma unroll
  for (int s = 0; s < 4; ++s) {
    int n = n0 + tx;
    tile[ty + s * 8][tx] = (n < 144) ? in[(size_t)(k0 + ty + s * 8) * 144 + n] : 0.f;
  }
  __syncthreads();
#pragma unroll
  for (int s = 0; s < 4; ++s) {
    int n = n0 + ty + s * 8;
    if (n < 144) out[(size_t)n * 1024 + k0 + tx] = (f16)tile[tx][ty + s * 8];
  }
}

// ---- lin1: yH = relu(x @ w + b) as f16, x (M,72), w (72,512) ----
__global__ __launch_bounds__(256) void k_lin1(const float* __restrict__ x,
                                              const float* __restrict__ w,
                                              const float* __restrict__ bias,
                                              f16* __restrict__ yH) {
  __shared__ float xs[8][72];
  int m0 = blockIdx.x * 8;
  int t = threadIdx.x;
  if (t < 144) {
    int row = t / 18, c4 = (t % 18) * 4;
    float4 v = *(const float4*)(x + (size_t)(m0 + row) * 72 + c4);
    xs[row][c4] = v.x; xs[row][c4 + 1] = v.y; xs[row][c4 + 2] = v.z; xs[row][c4 + 3] = v.w;
  }
  __syncthreads();
  int j0 = t, j1 = t + 256;
  float b0 = bias[j0], b1 = bias[j1];
  float acc[8][2];
#pragma unroll
  for (int r = 0; r < 8; ++r) { acc[r][0] = b0; acc[r][1] = b1; }
  for (int k = 0; k < 72; ++k) {
    float w0 = w[k * 512 + j0], w1 = w[k * 512 + j1];
#pragma unroll
    for (int r = 0; r < 8; ++r) {
      acc[r][0] = fmaf(xs[r][k], w0, acc[r][0]);
      acc[r][1] = fmaf(xs[r][k], w1, acc[r][1]);
    }
  }
#pragma unroll
  for (int r = 0; r < 8; ++r) {
    yH[(size_t)(m0 + r) * 512 + j0] = (f16)fmaxf(acc[r][0], 0.f);
    yH[(size_t)(m0 + r) * 512 + j1] = (f16)fmaxf(acc[r][1], 0.f);
  }
}

// ---- LayerNorm f16 -> f16 (one block per row), stats in f32 ----
template <int W>
__global__ __launch_bounds__(256) void k_ln(const f16* __restrict__ in,
                                            const float* __restrict__ g,
                                            const float* __restrict__ be,
                                            f16* __restrict__ out) {
  constexpr int V = W / 256;  // 2 or 4
  int row = blockIdx.x, t = threadIdx.x;
  const f16* p = in + (size_t)row * W + t * V;
  float v[V];
  if constexpr (V == 4) {
    union { uint2 u; f16 h[4]; } pk;
    pk.u = *(const uint2*)p;
#pragma unroll
    for (int i = 0; i < 4; ++i) v[i] = (float)pk.h[i];
  } else {
    union { unsigned u; f16 h[2]; } pk;
    pk.u = *(const unsigned*)p;
    v[0] = (float)pk.h[0]; v[1] = (float)pk.h[1];
  }
  float s = 0.f, ss = 0.f;
#pragma unroll
  for (int i = 0; i < V; ++i) { s += v[i]; ss += v[i] * v[i]; }
#pragma unroll
  for (int o = 32; o > 0; o >>= 1) { s += __shfl_down(s, o); ss += __shfl_down(ss, o); }
  __shared__ float red[10];
  if ((t & 63) == 0) { red[(t >> 6) * 2] = s; red[(t >> 6) * 2 + 1] = ss; }
  __syncthreads();
  if (t == 0) {
    float S = red[0] + red[2] + red[4] + red[6];
    float SS = red[1] + red[3] + red[5] + red[7];
    float mean = S / W;
    float var = SS / W - mean * mean;
    red[8] = mean; red[9] = rsqrtf(var + 1e-5f);
  }
  __syncthreads();
  float mean = red[8], rstd = red[9];
  if constexpr (V == 4) {
    union { f16 h[4]; uint2 u; } pk;
#pragma unroll
    for (int i = 0; i < 4; ++i) {
      int col = t * 4 + i;
      pk.h[i] = (f16)((v[i] - mean) * rstd * g[col] + be[col]);
    }
    *(uint2*)(out + (size_t)row * W + t * 4) = pk.u;
  } else {
    union { f16 h[2]; unsigned u; } pk;
#pragma unroll
    for (int i = 0; i < 2; ++i) {
      int col = t * 2 + i;
      pk.h[i] = (f16)((v[i] - mean) * rstd * g[col] + be[col]);
    }
    *(unsigned*)(out + (size_t)row * W + t * 2) = pk.u;
  }
}

// ---- pipelined GEMM: 128x128 tile, BK=32, 3-slot LDS ring (48 KB), counted vmcnt ----
// LDS chunk-plane layout (conflict-free, verified r9: BANK_CONFLICT=0):
//   elem(row,c) = (row>>4)*512 + (c*16 + (row&15))*8; staging pre-permutes the GLOBAL
//   source so the gl_lds dest stays linear.
// Ring: iter t reads slot t%3, stages tile t+2 into slot (t+2)%3 (freed by the barrier
// ending iter t-1); vmcnt(4) at iter end = tile t+1 landed, tile t+2 stays in flight.
// 48 KB -> 3 blocks/CU (r9's 64 KB/2-block version was occupancy-starved: 21% occ).
// No XCD swizzle: inputs are L3-resident; r9 swizzle re-streamed B per m-row chunk
// per XCD (4MB L2 < 6MB B) -> FETCH 142->308 MB regression.
template <int K>
__global__ __launch_bounds__(256, 3) void k_gemmp(const f16* __restrict__ A,
                                                  const f16* __restrict__ BT,
                                                  f16* __restrict__ C, int N) {
  constexpr int NT = K / 32;
  __shared__ __align__(16) f16 lds[24576];  // 48 KB: A slots [0,12288), B slots [12288,24576)
  const int tid = threadIdx.x, lane = tid & 63, wave = tid >> 6;
  const int wr = wave >> 1, wc = wave & 1;

  int n0 = blockIdx.x * 128, m0 = blockIdx.y * 128;

  // staging map: thread tid fetches global (row r1, 16B-chunk c1) and (r1+64, c1)
  const int r1 = ((tid >> 6) << 4) | (tid & 15);
  const int c1 = (tid >> 4) & 3;
  const f16* Asrc = A + (size_t)(m0 + r1) * K + c1 * 8;
  const f16* Bsrc = BT + (size_t)(n0 + r1) * K + c1 * 8;
  const int K64 = 64 * K;

  // frag-read offset: lane (c=l>>4, fr=l&15) -> chunk c*16+fr within its 16-row block
  const int rdA = ((lane >> 4) << 4) | (lane & 15);
  const int fA = wr * 2048 + rdA * 8;            // + i*512 per m-frag
  const int fB = 12288 + wc * 2048 + rdA * 8;    // + j*512 per n-frag

  f32x4 acc[4][4] = {};

#define STAGE(t)                                                \
  {                                                             \
    const f16* a_ = Asrc + (t) * 32;                            \
    const f16* b_ = Bsrc + (t) * 32;                            \
    f16* d_ = lds + ((t) % 3) * 4096 + wave * 512;              \
    gl16(a_, d_);                                               \
    gl16(a_ + K64, d_ + 2048);                                  \
    gl16(b_, d_ + 12288);                                       \
    gl16(b_ + K64, d_ + 14336);                                 \
  }

  STAGE(0) STAGE(1)
  asm volatile("s_waitcnt vmcnt(4)" ::: "memory");  // tile 0 landed (8 -> 4 outstanding)
  __builtin_amdgcn_s_barrier();

#define GITER(t, DOSTAGE, VMN, DOBAR)                                         \
  {                                                                           \
    if (DOSTAGE) STAGE((t) + 2);                                              \
    const int sb = ((t) % 3) * 4096;                                          \
    f16x8 af[4], bf[4];                                                       \
    _Pragma("unroll") for (int i = 0; i < 4; ++i)                             \
        af[i] = *(const f16x8*)&lds[sb + fA + i * 512];                       \
    _Pragma("unroll") for (int j = 0; j < 4; ++j)                             \
        bf[j] = *(const f16x8*)&lds[sb + fB + j * 512];                       \
    __builtin_amdgcn_s_setprio(1);                                            \
    _Pragma("unroll") for (int i = 0; i < 4; ++i)                             \
        _Pragma("unroll") for (int j = 0; j < 4; ++j)                         \
            acc[i][j] = __builtin_amdgcn_mfma_f32_16x16x32_f16(               \
                af[i], bf[j], acc[i][j], 0, 0, 0);                            \
    __builtin_amdgcn_s_setprio(0);                                            \
    __builtin_amdgcn_sched_barrier(0);                                        \
    if ((VMN) == 4) { asm volatile("s_waitcnt vmcnt(4)" ::: "memory"); }      \
    else if ((VMN) == 0) { asm volatile("s_waitcnt vmcnt(0)" ::: "memory"); } \
    if (DOBAR) __builtin_amdgcn_s_barrier();                                  \
  }

#pragma unroll 1
  for (int t = 0; t < NT - 2; ++t) GITER(t, true, 4, true)
  GITER(NT - 2, false, 0, true)
  GITER(NT - 1, false, -1, false)
#undef GITER
#undef STAGE

  const int fr = lane & 15, q = lane >> 4;
  int col = n0 + wc * 64 + fr;
  int rb = m0 + wr * 64 + q * 4;
#pragma unroll
  for (int i = 0; i < 4; ++i)
#pragma unroll
    for (int j = 0; j < 4; ++j)
#pragma unroll
      for (int r = 0; r < 4; ++r)
        C[(size_t)(rb + i * 16 + r) * N + col + j * 16] = (f16)acc[i][j][r];
}

// ---- SRU scan: 8-deep load ring + 16-deep h ring (store at +8, reuse at +16) ----
template <int KK>
__global__ __launch_bounds__(64) void k_scan(const f16* __restrict__ U,
                                             const f16* __restrict__ xln,
                                             const float* __restrict__ wcp,
                                             const float* __restrict__ bp,
                                             f16* __restrict__ yH,
                                             float* __restrict__ cs) {
  int tid = blockIdx.x * 64 + threadIdx.x;  // 0..32767
  int dir = tid >> 14, b = (tid >> 9) & 31, d = tid & 511;
  int col = (dir << 9) + d;
  const int N = 1024 * KK;
  const f16* base = U + dir * (512 * KK) + d;
  const f16* rbase = (KK == 4) ? base + 1536 : xln + col;
  const long rstride = (KK == 4) ? N : 1024;
  float wcf = wcp[col], wcr = wcp[1024 + col];
  float bfv = bp[col], brv = bp[1024 + col];
  float c = 0.f;
  f16 ru0[8], ru1[8], ru2[8], rr[8];
  float hh[16];

  const long sgn = dir ? -32L : 32L;
  const long sN = sgn * N, sR = sgn * rstride, sY = sgn * 1024;
  long row0 = ((long)(dir ? 511 : 0) << 5) + b;
  const f16* pL = base + (size_t)row0 * N;
  const f16* pR = rbase + (size_t)row0 * rstride;
#pragma unroll
  for (int i = 0; i < 8; ++i) {
    ru0[i] = pL[0]; ru1[i] = pL[512]; ru2[i] = pL[1024];
    rr[i] = *pR;
    pL += sN; pR += sR;
  }
  f16* pS = yH + (size_t)row0 * 1024 + col;

#define BODY(i, DO_STORE, DO_PRE)                                        \
  {                                                                      \
    float u0 = (float)ru0[(i) & 7], u1 = (float)ru1[(i) & 7],            \
          u2 = (float)ru2[(i) & 7], res = (float)rr[(i) & 7];            \
    if (DO_STORE) {                                                      \
      *pS = (f16)hh[((i) + 8) & 15];                                     \
      pS += sY;                                                          \
      __builtin_amdgcn_sched_barrier(0);                                 \
    }                                                                    \
    if (DO_PRE) {                                                        \
      ru0[(i) & 7] = pL[0]; ru1[(i) & 7] = pL[512];                      \
      ru2[(i) & 7] = pL[1024]; rr[(i) & 7] = *pR;                        \
      pL += sN; pR += sR;                                                \
    }                                                                    \
    float zf = u1 + wcf * c + bfv;                                       \
    float f = __builtin_amdgcn_rcpf(1.f + __expf(-zf));                  \
    c = f * c + (1.f - f) * u0;                                          \
    float zr = u2 + wcr * c + brv;                                       \
    float r = __builtin_amdgcn_rcpf(1.f + __expf(-zr));                  \
    hh[(i) & 15] = r * c + (1.f - r) * res;                              \
  }

#pragma unroll
  for (int i = 0; i < 16; ++i) BODY(i, (i >= 8), true);
  for (int t0 = 16; t0 < 496; t0 += 16) {
#pragma unroll
    for (int i = 0; i < 16; ++i) BODY(i, true, true);
  }
#pragma unroll
  for (int i = 0; i < 16; ++i) BODY(i, true, (i < 8));
#pragma unroll
  for (int j = 8; j < 16; ++j) { *pS = (f16)hh[j]; pS += sY; }
  cs[b * 1024 + col] = c;
#undef BODY
}

// ---- lin2 via MFMA: out(M,144) f32 = Y(M,1024) f16 @ WT(144,1024)^T + bias ----
__global__ __launch_bounds__(256) void k_lin2m(const f16* __restrict__ Y,
                                               const f16* __restrict__ WT,
                                               const float* __restrict__ bias,
                                               float* __restrict__ out) {
  __shared__ __align__(16) f16 lA[64 * 32];
  int m0 = blockIdx.x * 64;
  int tid = threadIdx.x, lane = tid & 63, wave = tid >> 6;
  int fr = lane & 15, kq = (lane >> 4) * 8;
  f32x4 acc[9] = {};
  int srow = wave * 16 + (lane >> 2);
  int skel = (lane & 3) * 8;
  const f16* Yp = Y + (size_t)(m0 + srow) * 1024 + skel;
  f16* ldst = lA + wave * 512;
  for (int k0 = 0; k0 < 1024; k0 += 32) {
    if (k0) __syncthreads();
    gl16(Yp + k0, ldst);
    f16x8 bf[9];
#pragma unroll
    for (int j = 0; j < 9; ++j)
      bf[j] = *(const f16x8*)(WT + (size_t)(j * 16 + fr) * 1024 + k0 + kq);
    __syncthreads();
    f16x8 af = *(const f16x8*)&lA[(wave * 16 + fr) * 32 + kq];
#pragma unroll
    for (int j = 0; j < 9; ++j)
      acc[j] = __builtin_amdgcn_mfma_f32_16x16x32_f16(af, bf[j], acc[j], 0, 0, 0);
  }
  int rb = m0 + wave * 16 + (lane >> 4) * 4;
#pragma unroll
  for (int j = 0; j < 9; ++j) {
    float bv = bias[j * 16 + fr];
#pragma unroll
    for (int r = 0; r < 4; ++r)
      out[(size_t)(rb + r) * 144 + j * 16 + fr] = acc[j][r] + bv;
  }
}

extern "C" void kernel_launch(void* const* d_in, const int* in_sizes, int n_in,
                              void* d_out, int out_size, void* d_ws, size_t ws_size,
                              hipStream_t stream) {
  const float* x      = (const float*)d_in[0];
  const float* lin1_w = (const float*)d_in[1];
  const float* lin1_b = (const float*)d_in[2];
  const float* lin2_w = (const float*)d_in[3];
  const float* lin2_b = (const float*)d_in[4];
  const float* W0     = (const float*)d_in[5];
  const float* wc0    = (const float*)d_in[6];
  const float* b0     = (const float*)d_in[7];
  const float* ln0_g  = (const float*)d_in[8];
  const float* ln0_b  = (const float*)d_in[9];
  const float* Wl     = (const float*)d_in[10];
  const float* wcl    = (const float*)d_in[11];
  const float* bl     = (const float*)d_in[12];
  const float* lnl_g  = (const float*)d_in[13];
  const float* lnl_b  = (const float*)d_in[14];
  float* out = (float*)d_out;

  // workspace layout (252 MB)
  char* ws = (char*)d_ws;
  f16* yH  = (f16*)(ws);                       // (16384,1024) f16, 32 MB
  f16* A16 = (f16*)(ws + ((size_t)32 << 20));  // (16384,1024) f16, 32 MB
  f16* C16 = (f16*)(ws + ((size_t)64 << 20));  // (16384,4096) f16, up to 128 MB
  f16* WT2 = (f16*)(ws + ((size_t)192 << 20)); // (144,1024) f16
  f16* W0T = (f16*)(ws + ((size_t)224 << 20)); // (4096,512) f16, 4 MB
  f16* WlT = (f16*)(ws + ((size_t)228 << 20)); // 4 x (3072,1024) f16, 24 MB

  k_transpose_perm<4><<<dim3(128, 16, 1), dim3(32, 8), 0, stream>>>(W0, W0T, 512, 4096);
  k_transpose_perm<3><<<dim3(96, 32, 4), dim3(32, 8), 0, stream>>>(Wl, WlT, 1024, 3072);

  k_lin1<<<MM / 8, 256, 0, stream>>>(x, lin1_w, lin1_b, yH);

  // layer 0 (k=4)
  k_ln<512><<<MM, 256, 0, stream>>>(yH, ln0_g, ln0_b, A16);
  k_gemmp<512><<<dim3(32, 128), 256, 0, stream>>>(A16, W0T, C16, 4096);
  k_scan<4><<<512, 64, 0, stream>>>(C16, (const f16*)nullptr, wc0, b0, yH, out + 2359296);

  k_transpose2<<<dim3(5, 32), dim3(32, 8), 0, stream>>>(lin2_w, WT2);

  // layers 1..4 (k=3)
  for (int i = 0; i < 4; ++i) {
    k_ln<1024><<<MM, 256, 0, stream>>>(yH, lnl_g + i * 1024, lnl_b + i * 1024, A16);
    k_gemmp<1024><<<dim3(24, 128), 256, 0, stream>>>(A16, WlT + (size_t)i * 3072 * 1024, C16, 3072);
    k_scan<3><<<512, 64, 0, stream>>>(C16, A16, wcl + i * 2048, bl + i * 2048, yH,
                                      out + 2359296 + (size_t)(i + 1) * 32768);
  }

  k_lin2m<<<MM / 64, 256, 0, stream>>>(yH, WT2, lin2_b, out);
}